// Round 1
// baseline (646.414 us; speedup 1.0000x reference)
//
#include <hip/hip_runtime.h>

// Problem constants (from reference): inputs (B,H,W,C) = (16,128,128,128) fp32,
// FACTOR = (2,2) half-pixel bilinear -> output (16,256,256,128) fp32.
#define B_  16
#define H_  128
#define W_  128
#define C_  128
#define HO_ 256
#define WO_ 256
#define C4_ 32   // C_/4 float4s per pixel

// Total output float4s = 16*256*256*32 = 33,554,432
// tid bit layout: [b:4][y:8][x:8][c4:5]

__global__ __launch_bounds__(256) void upsample2x_kernel(
    const float* __restrict__ in, float* __restrict__ out)
{
    const int tid = blockIdx.x * blockDim.x + threadIdx.x;

    const int c4 = tid & 31;
    const int x  = (tid >> 5)  & 255;
    const int y  = (tid >> 13) & 255;
    const int b  = tid >> 21;

    // Closed-form 2x half-pixel bilinear:
    //   even out index 2i: 0.25*in[i-1] + 0.75*in[i]   (lo clamped at 0)
    //   odd  out index 2i+1: 0.75*in[i] + 0.25*in[i+1] (hi clamped at n-1)
    // When lo==hi (edges) any weight yields the same value, matching the
    // reference's frac=0 convention.
    int iy = y >> 1;
    int lo_h, hi_h; float th;
    if (y & 1) { lo_h = iy;               hi_h = min(iy + 1, H_ - 1); th = 0.25f; }
    else       { lo_h = max(iy - 1, 0);   hi_h = iy;                  th = 0.75f; }

    int ix = x >> 1;
    int lo_w, hi_w; float tw;
    if (x & 1) { lo_w = ix;               hi_w = min(ix + 1, W_ - 1); tw = 0.25f; }
    else       { lo_w = max(ix - 1, 0);   hi_w = ix;                  tw = 0.75f; }

    const float4* __restrict__ in4 = reinterpret_cast<const float4*>(in);

    const int base_b = b * (H_ * W_ * C4_);
    const int r_lo = lo_h * (W_ * C4_);
    const int r_hi = hi_h * (W_ * C4_);
    const int c_lo = lo_w * C4_ + c4;
    const int c_hi = hi_w * C4_ + c4;

    float4 v00 = in4[base_b + r_lo + c_lo];
    float4 v01 = in4[base_b + r_lo + c_hi];
    float4 v10 = in4[base_b + r_hi + c_lo];
    float4 v11 = in4[base_b + r_hi + c_hi];

    // Match reference order: interpolate along H first, then W.
    const float ah = 1.0f - th;
    const float aw = 1.0f - tw;

    float4 xlo, xhi, r;
    xlo.x = v00.x * ah + v10.x * th;
    xlo.y = v00.y * ah + v10.y * th;
    xlo.z = v00.z * ah + v10.z * th;
    xlo.w = v00.w * ah + v10.w * th;

    xhi.x = v01.x * ah + v11.x * th;
    xhi.y = v01.y * ah + v11.y * th;
    xhi.z = v01.z * ah + v11.z * th;
    xhi.w = v01.w * ah + v11.w * th;

    r.x = xlo.x * aw + xhi.x * tw;
    r.y = xlo.y * aw + xhi.y * tw;
    r.z = xlo.z * aw + xhi.z * tw;
    r.w = xlo.w * aw + xhi.w * tw;

    reinterpret_cast<float4*>(out)[tid] = r;
}

extern "C" void kernel_launch(void* const* d_in, const int* in_sizes, int n_in,
                              void* d_out, int out_size, void* d_ws, size_t ws_size,
                              hipStream_t stream)
{
    const float* in = reinterpret_cast<const float*>(d_in[0]);
    float* out = reinterpret_cast<float*>(d_out);

    const int total4 = B_ * HO_ * WO_ * C4_;   // 33,554,432 float4 outputs
    const int block = 256;
    const int grid = total4 / block;           // 131,072 blocks

    upsample2x_kernel<<<grid, block, 0, stream>>>(in, out);
}

// Round 3
// 610.091 us; speedup vs baseline: 1.0595x; 1.0595x over previous
//
#include <hip/hip_runtime.h>

// 2x half-pixel bilinear upsample, (16,128,128,128) f32 NHWC -> (16,256,256,128).
// One thread computes a 2x2 output quad (rows 2i,2i+1 x cols 2j,2j+1) for one
// input pixel (i,j) from its 3x3 clamped neighborhood: 9 loads / 4 stores.
//
// Closed-form weights (FACTOR=2 half-pixel):
//   out[2k]   = 0.25*in[k-1] + 0.75*in[k]   (lo clamped at 0)
//   out[2k+1] = 0.75*in[k]   + 0.25*in[k+1] (hi clamped at n-1)
// Clamped edges give lo==hi -> weighted sum of identical values == the value,
// matching the reference's frac=0 convention.

#define B_  16
#define H_  128
#define W_  128
#define C4_ 32    // 128 channels / 4 per float4
#define HO_ 256
#define WO_ 256

typedef float f4 __attribute__((ext_vector_type(4)));

// tid bit layout: [b:4][i:7][j:7][c4:5] -> 8,388,608 threads (32768 blocks x 256)

__global__ __launch_bounds__(256) void upsample2x_quad_kernel(
    const float* __restrict__ in, float* __restrict__ out)
{
    const int tid = blockIdx.x * blockDim.x + threadIdx.x;

    const int c4 = tid & 31;
    const int j  = (tid >> 5)  & 127;
    const int i  = (tid >> 12) & 127;
    const int b  = tid >> 19;

    const int jm = max(j - 1, 0), jp = min(j + 1, W_ - 1);
    const int im = max(i - 1, 0), ip = min(i + 1, H_ - 1);

    const f4* __restrict__ in4 = reinterpret_cast<const f4*>(in);
    f4* __restrict__ out4 = reinterpret_cast<f4*>(out);

    const int base = b * (H_ * W_ * C4_);
    const int rm = base + im * (W_ * C4_);
    const int r0 = base + i  * (W_ * C4_);
    const int rp = base + ip * (W_ * C4_);
    const int cm = jm * C4_ + c4;
    const int c0 = j  * C4_ + c4;
    const int cp = jp * C4_ + c4;

    // 3x3 neighborhood (rows im,i,ip x cols jm,j,jp), 9 x 16B loads.
    f4 a00 = in4[rm + cm], a01 = in4[rm + c0], a02 = in4[rm + cp];
    f4 a10 = in4[r0 + cm], a11 = in4[r0 + c0], a12 = in4[r0 + cp];
    f4 a20 = in4[rp + cm], a21 = in4[rp + c0], a22 = in4[rp + cp];

    // Interpolate along H first (matches reference order).
    // Top output row (2i):    0.25*row[i-1] + 0.75*row[i]
    // Bottom output row (2i+1): 0.75*row[i] + 0.25*row[i+1]
    f4 tm = 0.25f * a00 + 0.75f * a10;
    f4 t0 = 0.25f * a01 + 0.75f * a11;
    f4 tp = 0.25f * a02 + 0.75f * a12;
    f4 bm = 0.75f * a10 + 0.25f * a20;
    f4 b0 = 0.75f * a11 + 0.25f * a21;
    f4 bp = 0.75f * a12 + 0.25f * a22;

    // Then along W.
    f4 oTL = 0.25f * tm + 0.75f * t0;   // (2i,   2j)
    f4 oTR = 0.75f * t0 + 0.25f * tp;   // (2i,   2j+1)
    f4 oBL = 0.25f * bm + 0.75f * b0;   // (2i+1, 2j)
    f4 oBR = 0.75f * b0 + 0.25f * bp;   // (2i+1, 2j+1)

    const int ob  = b * (HO_ * WO_ * C4_);
    const int orT = ob + (2 * i) * (WO_ * C4_);
    const int orB = orT + (WO_ * C4_);
    const int ocL = (2 * j) * C4_ + c4;
    const int ocR = ocL + C4_;

    // Output stream has zero reuse -> nontemporal stores keep it out of L2.
    __builtin_nontemporal_store(oTL, &out4[orT + ocL]);
    __builtin_nontemporal_store(oTR, &out4[orT + ocR]);
    __builtin_nontemporal_store(oBL, &out4[orB + ocL]);
    __builtin_nontemporal_store(oBR, &out4[orB + ocR]);
}

extern "C" void kernel_launch(void* const* d_in, const int* in_sizes, int n_in,
                              void* d_out, int out_size, void* d_ws, size_t ws_size,
                              hipStream_t stream)
{
    const float* in = reinterpret_cast<const float*>(d_in[0]);
    float* out = reinterpret_cast<float*>(d_out);

    const int total = B_ * H_ * W_ * C4_;   // 8,388,608 threads (one per input float4)
    const int block = 256;
    const int grid = total / block;          // 32,768 blocks

    upsample2x_quad_kernel<<<grid, block, 0, stream>>>(in, out);
}